// Round 5
// baseline (545.870 us; speedup 1.0000x reference)
//
#include <hip/hip_runtime.h>
#include <hip/hip_bf16.h>

#define Bb   16
#define FIN  64
#define FOUT 128
#define NN   2048
#define KK   20
#define LCAP 32      // capture list size (approx top-32), refined to exact top-20
#define BUFD 96      // per-row LDS candidate buffer depth (flush when cnt > BUFD-64)

typedef unsigned long long u64;
typedef __attribute__((ext_vector_type(8))) __bf16 bf16x8;
typedef __attribute__((ext_vector_type(4))) float  f32x4;

static __device__ __forceinline__ unsigned short f2bf(float f) {
  unsigned u = __float_as_uint(f);
  unsigned r = (u + 0x7fff + ((u >> 16) & 1)) >> 16;   // RNE
  return (unsigned short)r;
}
static __device__ __forceinline__ float bf2f(unsigned short b) {
  return __uint_as_float(((unsigned)b) << 16);
}
static __device__ __forceinline__ void gll16(const void* g, void* l) {
  __builtin_amdgcn_global_load_lds(
      (const __attribute__((address_space(1))) unsigned int*)g,
      (__attribute__((address_space(3))) unsigned int*)l, 16, 0, 0);
}

// ascending bitonic sort of one u32 per lane across the full wave
static __device__ __forceinline__ unsigned sort64u(unsigned v, int lane) {
#pragma unroll
  for (int size = 2; size <= 64; size <<= 1) {
#pragma unroll
    for (int stride = size >> 1; stride; stride >>= 1) {
      unsigned o = __shfl_xor(v, stride);
      bool keepmin = (((lane & size) == 0) == ((lane & stride) == 0));
      bool lt = o < v;
      v = keepmin ? (lt ? o : v) : (lt ? v : o);
    }
  }
  return v;
}

// merge sorted-asc 32-list (lanes 0..31; lanes>=32 hold UMAX) with sorted-asc s
// (64 lanes); returns updated sorted-asc top-32 list (lanes>=32 = UMAX).
static __device__ __forceinline__ unsigned merge32u(unsigned lst, unsigned s, int lane) {
  unsigned rs = __shfl(s, 31 - (lane & 31));
  unsigned v = lst < rs ? lst : rs;       // bitonic
#pragma unroll
  for (int stride = 16; stride; stride >>= 1) {
    unsigned o = __shfl_xor(v, stride);
    unsigned mn = v < o ? v : o, mx = v < o ? o : v;
    v = ((lane & stride) == 0) ? mn : mx;
  }
  return (lane >= 32) ? 0xFFFFFFFFu : v;
}

static __device__ __forceinline__ void flushrow(unsigned& lst, int& cnt, unsigned& thr,
                                                const unsigned* bufrow, int lane) {
  unsigned c0 = (lane < cnt) ? bufrow[lane] : 0xFFFFFFFFu;
  c0 = sort64u(c0, lane);
  lst = merge32u(lst, c0, lane);
  if (cnt > 64) {
    unsigned c1 = (lane + 64 < cnt) ? bufrow[64 + lane] : 0xFFFFFFFFu;
    c1 = sort64u(c1, lane);
    lst = merge32u(lst, c1, lane);
  }
  thr = __shfl(lst, 31);
  cnt = 0;
}

// ---------------------------------------------------------------- prep
__global__ __launch_bounds__(256) void k_prep(const float* __restrict__ x,
                                              unsigned short* __restrict__ xth,
                                              unsigned short* __restrict__ xtl,
                                              float* __restrict__ xt32,
                                              float* __restrict__ sq) {
  __shared__ float ts[FIN][65];
  int nt = blockIdx.x, b = blockIdx.y;
  int nbase = nt * 64, tid = threadIdx.x;
  for (int i = tid; i < 64 * 64; i += 256) {
    int f = i >> 6, j = i & 63;
    ts[f][j] = x[((size_t)b * FIN + f) * NN + nbase + j];
  }
  __syncthreads();
  if (tid < 64) {
    float s = 0.f;
#pragma unroll
    for (int f = 0; f < FIN; ++f) { float v = ts[f][tid]; s += v * v; }
    sq[b * NN + nbase + tid] = s;
  }
  for (int u = tid; u < 512; u += 256) {
    int lane = u & 63, ck = (u >> 6) & 1, pg = u >> 7;
    int j = pg * 16 + (lane & 15);
    int kg = lane >> 4;
    int fbase = ck * 32 + kg * 8;
    float v[8]; unsigned short h[8], l[8];
#pragma unroll
    for (int e = 0; e < 8; ++e) {
      v[e] = ts[fbase + e][j];
      h[e] = f2bf(v[e]);
      l[e] = f2bf(v[e] - bf2f(h[e]));
    }
    size_t po = (((size_t)b * (NN / 16) + (nbase >> 4) + pg) * 2 + ck) * 512 + lane * 8;
    ushort4* dh = (ushort4*)(xth + po);
    dh[0] = make_ushort4(h[0], h[1], h[2], h[3]);
    dh[1] = make_ushort4(h[4], h[5], h[6], h[7]);
    ushort4* dl = (ushort4*)(xtl + po);
    dl[0] = make_ushort4(l[0], l[1], l[2], l[3]);
    dl[1] = make_ushort4(l[4], l[5], l[6], l[7]);
    float* d32 = xt32 + ((size_t)b * NN + nbase + j) * FIN + fbase;
    *(float4*)d32       = make_float4(v[0], v[1], v[2], v[3]);
    *(float4*)(d32 + 4) = make_float4(v[4], v[5], v[6], v[7]);
  }
}

// ---------------------------------------------------------------- P/Q GEMM
__global__ __launch_bounds__(256) void k_pq(const float* __restrict__ x,
                                            const float* __restrict__ W,
                                            const float* __restrict__ bias,
                                            float* __restrict__ Pt,
                                            float* __restrict__ Qt) {
  __shared__ float Ws[64][68];
  __shared__ float xs[64][68];
  int L = blockIdx.x;
  int bl = L & 7, nt = (L >> 3) & 31, ot = (L >> 8) & 3, bh = L >> 10;
  int b = bl | (bh << 3);
  int tid = threadIdx.x;
  for (int i = tid; i < 64 * 64; i += 256) {
    int f = i & 63, r = i >> 6;
    int R = ot * 64 + r;
    float w;
    if (R < FOUT) w = W[R * 2 * FIN + f] - W[R * 2 * FIN + FIN + f];
    else          w = W[(R - FOUT) * 2 * FIN + FIN + f];
    Ws[r][f] = w;
  }
  const float* xb = x + (size_t)b * FIN * NN + nt * 64;
  for (int i = tid; i < 64 * 64; i += 256) {
    int nn = i & 63, f = i >> 6;
    xs[nn][f] = xb[(size_t)f * NN + nn];
  }
  __syncthreads();
  int tx = tid & 15, ty = tid >> 4;
  int r0 = ty * 4;
  float acc[4][4] = {};
#pragma unroll
  for (int f = 0; f < 64; f += 4) {
    float4 a[4], c[4];
#pragma unroll
    for (int i = 0; i < 4; ++i) a[i] = *(const float4*)&Ws[r0 + i][f];
#pragma unroll
    for (int j = 0; j < 4; ++j) c[j] = *(const float4*)&xs[tx + 16 * j][f];
#pragma unroll
    for (int i = 0; i < 4; ++i)
#pragma unroll
      for (int j = 0; j < 4; ++j)
        acc[i][j] += a[i].x * c[j].x + a[i].y * c[j].y + a[i].z * c[j].z + a[i].w * c[j].w;
  }
  __syncthreads();                       // done reading Ws -> reuse as transpose buf
  float (*ts)[68] = Ws;
#pragma unroll
  for (int i = 0; i < 4; ++i) {
    int R = ot * 64 + r0 + i;
    float add = (R < FOUT) ? bias[R] : 0.f;
#pragma unroll
    for (int j = 0; j < 4; ++j)
      ts[tx + 16 * j][r0 + i] = acc[i][j] + add;
  }
  __syncthreads();
  float* dst = (ot < 2) ? Pt : Qt;
  int obase = (ot & 1) * 64;
  for (int i = tid; i < 4096; i += 256) {
    int n_l = i >> 6, o_l = i & 63;
    dst[((size_t)b * NN + nt * 64 + n_l) * FOUT + obase + o_l] = ts[n_l][o_l];
  }
}

// ---------------------------------------------------------------- kNN
// MFMA distance tiles -> packed u32 keys -> ballot+scatter candidate buffer
// -> amortized bitonic sort+merge into register top-32 -> exact fp64 refine.
__global__ __launch_bounds__(512, 8) void k_knn(const unsigned short* __restrict__ xth,
                                                const unsigned short* __restrict__ xtl,
                                                const float* __restrict__ xt32,
                                                const float* __restrict__ sq,
                                                int* __restrict__ knn) {
  __shared__ unsigned short BjH[4096];   // 8 KB
  __shared__ unsigned short BjL[4096];   // 8 KB
  __shared__ unsigned dtk[32][66];       // 8.25 KB packed keys
  __shared__ unsigned buf[32 * BUFD];    // 12 KB candidate buffers
  __shared__ float sqi_s[32], sqj_s[64];

  int L = blockIdx.x;
  int b = (L & 7) | ((L >> 9) << 3);     // XCD-local b
  int it = (L >> 3) & 63;
  int ibase = it * 32, tid = threadIdx.x;
  int lane = tid & 63, w = tid >> 6;     // 8 waves
  int tr = w >> 2, tc = w & 3;           // MFMA tile (2x4)

  const unsigned short* xhB = xth + (size_t)b * (NN / 16) * 1024;
  const unsigned short* xlB = xtl + (size_t)b * (NN / 16) * 1024;

  size_t pa = ((size_t)(ibase >> 4) + tr) * 1024;
  bf16x8 ah0 = *(const bf16x8*)(xhB + pa +       lane * 8);
  bf16x8 ah1 = *(const bf16x8*)(xhB + pa + 512 + lane * 8);
  bf16x8 al0 = *(const bf16x8*)(xlB + pa +       lane * 8);
  bf16x8 al1 = *(const bf16x8*)(xlB + pa + 512 + lane * 8);

  if (tid < 32) sqi_s[tid] = sq[b * NN + ibase + tid];

  unsigned lst[4], thr[4]; int cnt[4];
#pragma unroll
  for (int r = 0; r < 4; ++r) { lst[r] = 0xFFFFFFFFu; thr[r] = 0xFFFFFFFFu; cnt[r] = 0; }

  gll16(xhB + tid * 8, BjH + tid * 8);
  gll16(xlB + tid * 8, BjL + tid * 8);
  if (tid < 64) sqj_s[tid] = sq[b * NN + tid];

  for (int jt = 0; jt < NN / 64; ++jt) {
    __syncthreads();                     // staged tile + sqj ready
    {
      int jbase = jt * 64;
      bf16x8 bh0 = *(const bf16x8*)(BjH + (tc * 2 + 0) * 512 + lane * 8);
      bf16x8 bh1 = *(const bf16x8*)(BjH + (tc * 2 + 1) * 512 + lane * 8);
      bf16x8 bl0 = *(const bf16x8*)(BjL + (tc * 2 + 0) * 512 + lane * 8);
      bf16x8 bl1 = *(const bf16x8*)(BjL + (tc * 2 + 1) * 512 + lane * 8);
      f32x4 acc = {0.f, 0.f, 0.f, 0.f};
      acc = __builtin_amdgcn_mfma_f32_16x16x32_bf16(ah0, bh0, acc, 0, 0, 0);
      acc = __builtin_amdgcn_mfma_f32_16x16x32_bf16(ah1, bh1, acc, 0, 0, 0);
      acc = __builtin_amdgcn_mfma_f32_16x16x32_bf16(ah0, bl0, acc, 0, 0, 0);
      acc = __builtin_amdgcn_mfma_f32_16x16x32_bf16(ah1, bl1, acc, 0, 0, 0);
      acc = __builtin_amdgcn_mfma_f32_16x16x32_bf16(al0, bh0, acc, 0, 0, 0);
      acc = __builtin_amdgcn_mfma_f32_16x16x32_bf16(al1, bh1, acc, 0, 0, 0);
      int jl = tc * 16 + (lane & 15);
      int jglob = jbase + jl;
      float sj = sqj_s[jl];
#pragma unroll
      for (int e = 0; e < 4; ++e) {
        int il = tr * 16 + (lane >> 4) * 4 + e;
        float d = fmaxf(sqi_s[il] + sj - 2.f * acc[e], 0.f);
        unsigned key = (__float_as_uint(d) & 0xFFFFF800u) | (unsigned)jglob;
        if (jglob == ibase + il) key = 0xFFFFFFFFu;   // exclude self
        dtk[il][jl] = key;
      }
    }
    __syncthreads();                     // keys ready, Bj free
    if (jt + 1 < NN / 64) {              // prefetch next tile under selection
      const unsigned short* sh = xhB + (size_t)(jt + 1) * 4096;
      const unsigned short* sl = xlB + (size_t)(jt + 1) * 4096;
      gll16(sh + tid * 8, BjH + tid * 8);
      gll16(sl + tid * 8, BjL + tid * 8);
      if (tid < 64) sqj_s[tid] = sq[b * NN + (jt + 1) * 64 + tid];
    }
    // ---- compact survivors (1 ballot + scatter per row)
    u64 below = (1ull << lane) - 1;
#pragma unroll
    for (int r = 0; r < 4; ++r) {
      unsigned key = dtk[w * 4 + r][lane];
      u64 m = __ballot(key < thr[r]);
      if (m) {
        if (key < thr[r]) buf[(w * 4 + r) * BUFD + cnt[r] + __popcll(m & below)] = key;
        cnt[r] += (int)__popcll(m);
      }
    }
    if (cnt[0] > BUFD - 64 || cnt[1] > BUFD - 64 || cnt[2] > BUFD - 64 || cnt[3] > BUFD - 64) {
#pragma unroll
      for (int r = 0; r < 4; ++r)
        flushrow(lst[r], cnt[r], thr[r], &buf[(w * 4 + r) * BUFD], lane);
    }
  }
  // final flush
#pragma unroll
  for (int r = 0; r < 4; ++r)
    flushrow(lst[r], cnt[r], thr[r], &buf[(w * 4 + r) * BUFD], lane);

  // ---- exact fp64 refine of the 32 captured candidates, emit top-20
  const float* x32B = xt32 + (size_t)b * NN * FIN;
#pragma unroll
  for (int r = 0; r < 4; ++r) {
    int row = w * 4 + r, iglob = ibase + row;
    int j = (lane < LCAP) ? (int)(lst[r] & 0x7FFu) : -1;
    double dd = 1e300;
    if (j >= 0) {
      const float4* xi4 = (const float4*)(x32B + (size_t)iglob * FIN);
      const float4* xj4 = (const float4*)(x32B + (size_t)j * FIN);
      double s = 0.0;
#pragma unroll
      for (int q = 0; q < 16; ++q) {
        float4 a = xi4[q], c = xj4[q];
        double d0 = (double)a.x - (double)c.x;
        double d1 = (double)a.y - (double)c.y;
        double d2 = (double)a.z - (double)c.z;
        double d3 = (double)a.w - (double)c.w;
        s += d0 * d0 + d1 * d1 + d2 * d2 + d3 * d3;
      }
      dd = s;
    }
#pragma unroll
    for (int size = 2; size <= 64; size <<= 1) {
#pragma unroll
      for (int stride = size >> 1; stride; stride >>= 1) {
        double od = __shfl_xor(dd, stride);
        int    oj = __shfl_xor(j, stride);
        bool up = (lane & size) == 0;
        bool lower = (lane & stride) == 0;
        bool lt = (od < dd) || (od == dd && ((unsigned)oj < (unsigned)j));
        bool take = (lower == up) ? lt : !lt;
        if (take) { dd = od; j = oj; }
      }
    }
    if (lane < KK) knn[((size_t)b * NN + iglob) * KK + lane] = j;
  }
}

// ---------------------------------------------------------------- stats
__global__ __launch_bounds__(512) void k_stats(const float* __restrict__ Pt,
                                               const float* __restrict__ Qt,
                                               const int* __restrict__ knn,
                                               float* __restrict__ mxT,
                                               float* __restrict__ mnT,
                                               double* __restrict__ sums) {
  __shared__ int ks[64 * KK];           // 5 KB
  __shared__ float rs[2][4][FOUT];      // 4 KB
  int L = blockIdx.x;                   // 512 blocks
  int b = (L & 7) | ((L >> 8) << 3);
  int nt = (L >> 3) & 31;
  int tid = threadIdx.x;
  int o = tid & 127, ng = tid >> 7;
  int nbase = nt * 64;
  for (int i = tid; i < 64 * KK; i += 512)
    ks[i] = knn[((size_t)b * NN + nbase) * KK + i];
  __syncthreads();
  const float* PtB = Pt + (size_t)b * NN * FOUT + o;
  const float* QtB = Qt + (size_t)b * NN * FOUT + o;
  float s1 = 0.f, s2 = 0.f;
  for (int nl = ng * 16; nl < ng * 16 + 16; ++nl) {
    int n = nbase + nl;
    float p = PtB[(size_t)n * FOUT];
    float vmx = -3.4e38f, vmn = 3.4e38f;
#pragma unroll
    for (int k = 0; k < KK; ++k) {
      float q = QtB[(size_t)ks[nl * KK + k] * FOUT];
      float y = p + q;
      s1 += y; s2 = fmaf(y, y, s2);
      vmx = fmaxf(vmx, y); vmn = fminf(vmn, y);
    }
    mxT[((size_t)b * NN + n) * FOUT + o] = vmx;
    mnT[((size_t)b * NN + n) * FOUT + o] = vmn;
  }
  rs[0][ng][o] = s1; rs[1][ng][o] = s2;
  __syncthreads();
  if (tid < FOUT) {
    float a = rs[0][0][tid] + rs[0][1][tid] + rs[0][2][tid] + rs[0][3][tid];
    float c = rs[1][0][tid] + rs[1][1][tid] + rs[1][2][tid] + rs[1][3][tid];
    atomicAdd(&sums[tid], (double)a);
    atomicAdd(&sums[FOUT + tid], (double)c);
  }
}

// ---------------------------------------------------------------- epilogue (finalize fused)
__global__ __launch_bounds__(256) void k_out(const float* __restrict__ mxT,
                                             const float* __restrict__ mnT,
                                             const double* __restrict__ sums,
                                             const float* __restrict__ gamma,
                                             const float* __restrict__ beta,
                                             float* __restrict__ out) {
  __shared__ float ssl[2][FOUT];
  __shared__ float ts[64][65];
  int tid = threadIdx.x;
  if (tid < FOUT) {
    double cnt = (double)Bb * NN * KK;
    double mean = sums[tid] / cnt;
    double var = sums[FOUT + tid] / cnt - mean * mean;
    double inv = 1.0 / sqrt(var + 1e-5);
    double scale = (double)gamma[tid] * inv;
    ssl[0][tid] = (float)scale;
    ssl[1][tid] = (float)((double)beta[tid] - mean * scale);
  }
  __syncthreads();
  int L = blockIdx.x;
  int b = (L & 7) | ((L >> 9) << 3);
  int nt = (L >> 3) & 31, ot = (L >> 8) & 1;
  int nbase = nt * 64, obase = ot * 64;
  for (int i = tid; i < 4096; i += 256) {
    int o_l = i & 63, n_l = i >> 6;
    int o = obase + o_l;
    const float* src = (ssl[0][o] >= 0.f) ? mxT : mnT;
    ts[o_l][n_l] = src[((size_t)b * NN + nbase + n_l) * FOUT + o];
  }
  __syncthreads();
  for (int i = tid; i < 4096; i += 256) {
    int n_l = i & 63, o_l = i >> 6;
    int o = obase + o_l;
    out[((size_t)b * FOUT + o) * NN + nbase + n_l] =
        fmaxf(fmaf(ssl[0][o], ts[o_l][n_l], ssl[1][o]), 0.f);
  }
}

// ---------------------------------------------------------------- launch
extern "C" void kernel_launch(void* const* d_in, const int* in_sizes, int n_in,
                              void* d_out, int out_size, void* d_ws, size_t ws_size,
                              hipStream_t stream) {
  const float* x     = (const float*)d_in[0];
  const float* W     = (const float*)d_in[1];
  const float* bias  = (const float*)d_in[2];
  const float* gamma = (const float*)d_in[3];
  const float* beta  = (const float*)d_in[4];
  float* out = (float*)d_out;

  char* ws = (char*)d_ws;
  const size_t PN = (size_t)Bb * FOUT * NN;          // 4,194,304
  float* Pt = (float*)ws;  ws += PN * 4;
  float* Qt = (float*)ws;  ws += PN * 4;
  float* mxT = (float*)ws; ws += PN * 4;             // 16 MB, aliased with xt*
  float* mnT = (float*)ws; ws += PN * 4;
  float* sq = (float*)ws;  ws += (size_t)Bb * NN * 4;
  int*   knn = (int*)ws;   ws += (size_t)Bb * NN * KK * 4;
  double* sums = (double*)ws; ws += 2 * FOUT * 8;

  // xth/xtl/xt32 alias mxT (4+4+8 MB); k_stats overwrites mxT only after
  // k_knn finished reading them (stream-ordered).
  unsigned short* xth = (unsigned short*)mxT;
  unsigned short* xtl = xth + (size_t)Bb * NN * FIN;
  float* xt32 = (float*)(xtl + (size_t)Bb * NN * FIN);

  hipMemsetAsync(sums, 0, 2 * FOUT * 8, stream);

  k_prep<<<dim3(NN / 64, Bb), 256, 0, stream>>>(x, xth, xtl, xt32, sq);
  k_pq<<<2048, 256, 0, stream>>>(x, W, bias, Pt, Qt);
  k_knn<<<1024, 512, 0, stream>>>(xth, xtl, xt32, sq, knn);
  k_stats<<<512, 512, 0, stream>>>(Pt, Qt, knn, mxT, mnT, sums);
  k_out<<<1024, 256, 0, stream>>>(mxT, mnT, sums, gamma, beta, out);
}

// Round 6
// 398.103 us; speedup vs baseline: 1.3712x; 1.3712x over previous
//
#include <hip/hip_runtime.h>
#include <hip/hip_bf16.h>

#define Bb   16
#define FIN  64
#define FOUT 128
#define NN   2048
#define KK   20
#define LCAP 32      // capture list size (approx top-32), refined to exact top-20
#define BUFD 192     // per-row LDS candidate buffer depth
#define TRIP 64      // set flush flag when cnt exceeds this (flush next tile)

typedef unsigned long long u64;
typedef __attribute__((ext_vector_type(8))) __bf16 bf16x8;
typedef __attribute__((ext_vector_type(4))) float  f32x4;

static __device__ __forceinline__ unsigned short f2bf(float f) {
  unsigned u = __float_as_uint(f);
  unsigned r = (u + 0x7fff + ((u >> 16) & 1)) >> 16;   // RNE
  return (unsigned short)r;
}
static __device__ __forceinline__ float bf2f(unsigned short b) {
  return __uint_as_float(((unsigned)b) << 16);
}
static __device__ __forceinline__ void gll16(const void* g, void* l) {
  __builtin_amdgcn_global_load_lds(
      (const __attribute__((address_space(1))) unsigned int*)g,
      (__attribute__((address_space(3))) unsigned int*)l, 16, 0, 0);
}

// ascending bitonic sort of one u32 per lane across the full wave
static __device__ __forceinline__ unsigned sort64u(unsigned v, int lane) {
#pragma unroll
  for (int size = 2; size <= 64; size <<= 1) {
#pragma unroll
    for (int stride = size >> 1; stride; stride >>= 1) {
      unsigned o = __shfl_xor(v, stride);
      bool keepmin = (((lane & size) == 0) == ((lane & stride) == 0));
      bool lt = o < v;
      v = keepmin ? (lt ? o : v) : (lt ? v : o);
    }
  }
  return v;
}

// merge sorted-asc 32-list (lanes 0..31; lanes>=32 hold UMAX) with sorted-asc s
// (64 lanes); returns updated sorted-asc top-32 list (lanes>=32 = UMAX).
static __device__ __forceinline__ unsigned merge32u(unsigned lst, unsigned s, int lane) {
  unsigned rs = __shfl(s, 31 - (lane & 31));
  unsigned v = lst < rs ? lst : rs;       // bitonic
#pragma unroll
  for (int stride = 16; stride; stride >>= 1) {
    unsigned o = __shfl_xor(v, stride);
    unsigned mn = v < o ? v : o, mx = v < o ? o : v;
    v = ((lane & stride) == 0) ? mn : mx;
  }
  return (lane >= 32) ? 0xFFFFFFFFu : v;
}

static __device__ __forceinline__ void flushrow(unsigned& lst, int& cnt, unsigned& thr,
                                                const unsigned* bufrow, int lane) {
  for (int base = 0; base < cnt; base += 64) {
    unsigned c = (base + lane < cnt) ? bufrow[base + lane] : 0xFFFFFFFFu;
    c = sort64u(c, lane);
    lst = merge32u(lst, c, lane);
  }
  thr = __shfl(lst, 31);
  cnt = 0;
}

// ---------------------------------------------------------------- prep
__global__ __launch_bounds__(256) void k_prep(const float* __restrict__ x,
                                              unsigned short* __restrict__ xth,
                                              unsigned short* __restrict__ xtl,
                                              float* __restrict__ xt32,
                                              float* __restrict__ sq) {
  __shared__ float ts[FIN][65];
  int nt = blockIdx.x, b = blockIdx.y;
  int nbase = nt * 64, tid = threadIdx.x;
  for (int i = tid; i < 64 * 64; i += 256) {
    int f = i >> 6, j = i & 63;
    ts[f][j] = x[((size_t)b * FIN + f) * NN + nbase + j];
  }
  __syncthreads();
  if (tid < 64) {
    float s = 0.f;
#pragma unroll
    for (int f = 0; f < FIN; ++f) { float v = ts[f][tid]; s += v * v; }
    sq[b * NN + nbase + tid] = s;
  }
  for (int u = tid; u < 512; u += 256) {
    int lane = u & 63, ck = (u >> 6) & 1, pg = u >> 7;
    int j = pg * 16 + (lane & 15);
    int kg = lane >> 4;
    int fbase = ck * 32 + kg * 8;
    float v[8]; unsigned short h[8], l[8];
#pragma unroll
    for (int e = 0; e < 8; ++e) {
      v[e] = ts[fbase + e][j];
      h[e] = f2bf(v[e]);
      l[e] = f2bf(v[e] - bf2f(h[e]));
    }
    size_t po = (((size_t)b * (NN / 16) + (nbase >> 4) + pg) * 2 + ck) * 512 + lane * 8;
    ushort4* dh = (ushort4*)(xth + po);
    dh[0] = make_ushort4(h[0], h[1], h[2], h[3]);
    dh[1] = make_ushort4(h[4], h[5], h[6], h[7]);
    ushort4* dl = (ushort4*)(xtl + po);
    dl[0] = make_ushort4(l[0], l[1], l[2], l[3]);
    dl[1] = make_ushort4(l[4], l[5], l[6], l[7]);
    float* d32 = xt32 + ((size_t)b * NN + nbase + j) * FIN + fbase;
    *(float4*)d32       = make_float4(v[0], v[1], v[2], v[3]);
    *(float4*)(d32 + 4) = make_float4(v[4], v[5], v[6], v[7]);
  }
}

// ---------------------------------------------------------------- P/Q GEMM
// Emits TRANSPOSED Pt[b][n][o] (bias added) and Qt[b][n][o]. (round-4 form:
// dedicated transpose LDS; the Ws-reuse variant ballooned VGPR to 256.)
__global__ __launch_bounds__(256) void k_pq(const float* __restrict__ x,
                                            const float* __restrict__ W,
                                            const float* __restrict__ bias,
                                            float* __restrict__ Pt,
                                            float* __restrict__ Qt) {
  __shared__ float Ws[64][68];
  __shared__ float xs[64][68];
  __shared__ float ts[64][65];
  int L = blockIdx.x;
  int bl = L & 7, nt = (L >> 3) & 31, ot = (L >> 8) & 3, bh = L >> 10;
  int b = bl | (bh << 3);
  int tid = threadIdx.x;
  for (int i = tid; i < 64 * 64; i += 256) {
    int f = i & 63, r = i >> 6;
    int R = ot * 64 + r;
    float w;
    if (R < FOUT) w = W[R * 2 * FIN + f] - W[R * 2 * FIN + FIN + f];
    else          w = W[(R - FOUT) * 2 * FIN + FIN + f];
    Ws[r][f] = w;
  }
  const float* xb = x + (size_t)b * FIN * NN + nt * 64;
  for (int i = tid; i < 64 * 64; i += 256) {
    int nn = i & 63, f = i >> 6;
    xs[nn][f] = xb[(size_t)f * NN + nn];
  }
  __syncthreads();
  int tx = tid & 15, ty = tid >> 4;
  int r0 = ty * 4;
  float acc[4][4] = {};
#pragma unroll
  for (int f = 0; f < 64; f += 4) {
    float4 a[4], c[4];
#pragma unroll
    for (int i = 0; i < 4; ++i) a[i] = *(const float4*)&Ws[r0 + i][f];
#pragma unroll
    for (int j = 0; j < 4; ++j) c[j] = *(const float4*)&xs[tx + 16 * j][f];
#pragma unroll
    for (int i = 0; i < 4; ++i)
#pragma unroll
      for (int j = 0; j < 4; ++j)
        acc[i][j] += a[i].x * c[j].x + a[i].y * c[j].y + a[i].z * c[j].z + a[i].w * c[j].w;
  }
#pragma unroll
  for (int i = 0; i < 4; ++i) {
    int R = ot * 64 + r0 + i;
    float add = (R < FOUT) ? bias[R] : 0.f;
#pragma unroll
    for (int j = 0; j < 4; ++j)
      ts[tx + 16 * j][r0 + i] = acc[i][j] + add;
  }
  __syncthreads();
  float* dst = (ot < 2) ? Pt : Qt;
  int obase = (ot & 1) * 64;
  for (int i = tid; i < 4096; i += 256) {
    int n_l = i >> 6, o_l = i & 63;
    dst[((size_t)b * NN + nt * 64 + n_l) * FOUT + obase + o_l] = ts[n_l][o_l];
  }
}

// ---------------------------------------------------------------- kNN
// MFMA distance tiles -> packed u32 keys -> ballot+scatter candidate buffer
// -> BLOCK-UNIFORM deferred flush (flag set when any wave trips; all waves
// flush together next tile) -> exact fp64 refine.
__global__ __launch_bounds__(512, 8) void k_knn(const unsigned short* __restrict__ xth,
                                                const unsigned short* __restrict__ xtl,
                                                const float* __restrict__ xt32,
                                                const float* __restrict__ sq,
                                                int* __restrict__ knn) {
  __shared__ unsigned short BjH[4096];   // 8 KB
  __shared__ unsigned short BjL[4096];   // 8 KB
  __shared__ unsigned dtk[32][66];       // 8.25 KB packed keys
  __shared__ unsigned buf[32 * BUFD];    // 24 KB candidate buffers
  __shared__ float sqi_s[32], sqj_s[64];
  __shared__ unsigned flg[2];

  int L = blockIdx.x;
  int b = (L & 7) | ((L >> 9) << 3);     // XCD-local b
  int it = (L >> 3) & 63;
  int ibase = it * 32, tid = threadIdx.x;
  int lane = tid & 63, w = tid >> 6;     // 8 waves
  int tr = w >> 2, tc = w & 3;           // MFMA tile (2x4)

  const unsigned short* xhB = xth + (size_t)b * (NN / 16) * 1024;
  const unsigned short* xlB = xtl + (size_t)b * (NN / 16) * 1024;

  size_t pa = ((size_t)(ibase >> 4) + tr) * 1024;
  bf16x8 ah0 = *(const bf16x8*)(xhB + pa +       lane * 8);
  bf16x8 ah1 = *(const bf16x8*)(xhB + pa + 512 + lane * 8);
  bf16x8 al0 = *(const bf16x8*)(xlB + pa +       lane * 8);
  bf16x8 al1 = *(const bf16x8*)(xlB + pa + 512 + lane * 8);

  if (tid < 32) sqi_s[tid] = sq[b * NN + ibase + tid];
  if (tid < 2) flg[tid] = 0;

  unsigned lst[4], thr[4]; int cnt[4];
#pragma unroll
  for (int r = 0; r < 4; ++r) { lst[r] = 0xFFFFFFFFu; thr[r] = 0xFFFFFFFFu; cnt[r] = 0; }

  gll16(xhB + tid * 8, BjH + tid * 8);
  gll16(xlB + tid * 8, BjL + tid * 8);
  if (tid < 64) sqj_s[tid] = sq[b * NN + tid];

  for (int jt = 0; jt < NN / 64; ++jt) {
    __syncthreads();                     // bar1: staged tile + sqj + flag ops ordered
    if (tid == 0) flg[(jt & 1) ^ 1] = 0; // clear slot read last tile (reads were
                                         // pre-bar1; sets to it happen post-bar2)
    {
      int jbase = jt * 64;
      bf16x8 bh0 = *(const bf16x8*)(BjH + (tc * 2 + 0) * 512 + lane * 8);
      bf16x8 bh1 = *(const bf16x8*)(BjH + (tc * 2 + 1) * 512 + lane * 8);
      bf16x8 bl0 = *(const bf16x8*)(BjL + (tc * 2 + 0) * 512 + lane * 8);
      bf16x8 bl1 = *(const bf16x8*)(BjL + (tc * 2 + 1) * 512 + lane * 8);
      f32x4 acc = {0.f, 0.f, 0.f, 0.f};
      acc = __builtin_amdgcn_mfma_f32_16x16x32_bf16(ah0, bh0, acc, 0, 0, 0);
      acc = __builtin_amdgcn_mfma_f32_16x16x32_bf16(ah1, bh1, acc, 0, 0, 0);
      acc = __builtin_amdgcn_mfma_f32_16x16x32_bf16(ah0, bl0, acc, 0, 0, 0);
      acc = __builtin_amdgcn_mfma_f32_16x16x32_bf16(ah1, bl1, acc, 0, 0, 0);
      acc = __builtin_amdgcn_mfma_f32_16x16x32_bf16(al0, bh0, acc, 0, 0, 0);
      acc = __builtin_amdgcn_mfma_f32_16x16x32_bf16(al1, bh1, acc, 0, 0, 0);
      int jl = tc * 16 + (lane & 15);
      int jglob = jbase + jl;
      float sj = sqj_s[jl];
#pragma unroll
      for (int e = 0; e < 4; ++e) {
        int il = tr * 16 + (lane >> 4) * 4 + e;
        float d = fmaxf(sqi_s[il] + sj - 2.f * acc[e], 0.f);
        unsigned key = (__float_as_uint(d) & 0xFFFFF800u) | (unsigned)jglob;
        if (jglob == ibase + il) key = 0xFFFFFFFFu;   // exclude self
        dtk[il][jl] = key;
      }
    }
    __syncthreads();                     // bar2: keys ready, Bj free
    int doflush = flg[jt & 1];           // set during previous tile
    if (jt + 1 < NN / 64) {              // prefetch next tile under selection
      const unsigned short* sh = xhB + (size_t)(jt + 1) * 4096;
      const unsigned short* sl = xlB + (size_t)(jt + 1) * 4096;
      gll16(sh + tid * 8, BjH + tid * 8);
      gll16(sl + tid * 8, BjL + tid * 8);
      if (tid < 64) sqj_s[tid] = sq[b * NN + (jt + 1) * 64 + tid];
    }
    // ---- compact survivors (1 ballot + scatter per row)
    u64 below = (1ull << lane) - 1;
#pragma unroll
    for (int r = 0; r < 4; ++r) {
      unsigned key = dtk[w * 4 + r][lane];
      u64 m = __ballot(key < thr[r]);
      if (m) {
        if (key < thr[r]) buf[(w * 4 + r) * BUFD + cnt[r] + __popcll(m & below)] = key;
        cnt[r] += (int)__popcll(m);
      }
    }
    // ---- block-uniform flush (decided last tile), then trip check for next
    if (doflush) {
#pragma unroll
      for (int r = 0; r < 4; ++r)
        flushrow(lst[r], cnt[r], thr[r], &buf[(w * 4 + r) * BUFD], lane);
    }
    bool trip = cnt[0] > TRIP || cnt[1] > TRIP || cnt[2] > TRIP || cnt[3] > TRIP;
    if (trip && lane == 0) flg[(jt & 1) ^ 1] = 1;
  }
  // final flush
#pragma unroll
  for (int r = 0; r < 4; ++r)
    flushrow(lst[r], cnt[r], thr[r], &buf[(w * 4 + r) * BUFD], lane);

  // ---- exact fp64 refine of the 32 captured candidates, emit top-20
  const float* x32B = xt32 + (size_t)b * NN * FIN;
#pragma unroll
  for (int r = 0; r < 4; ++r) {
    int row = w * 4 + r, iglob = ibase + row;
    int j = (lane < LCAP) ? (int)(lst[r] & 0x7FFu) : -1;
    double dd = 1e300;
    if (j >= 0) {
      const float4* xi4 = (const float4*)(x32B + (size_t)iglob * FIN);
      const float4* xj4 = (const float4*)(x32B + (size_t)j * FIN);
      double s = 0.0;
#pragma unroll
      for (int q = 0; q < 16; ++q) {
        float4 a = xi4[q], c = xj4[q];
        double d0 = (double)a.x - (double)c.x;
        double d1 = (double)a.y - (double)c.y;
        double d2 = (double)a.z - (double)c.z;
        double d3 = (double)a.w - (double)c.w;
        s += d0 * d0 + d1 * d1 + d2 * d2 + d3 * d3;
      }
      dd = s;
    }
#pragma unroll
    for (int size = 2; size <= 64; size <<= 1) {
#pragma unroll
      for (int stride = size >> 1; stride; stride >>= 1) {
        double od = __shfl_xor(dd, stride);
        int    oj = __shfl_xor(j, stride);
        bool up = (lane & size) == 0;
        bool lower = (lane & stride) == 0;
        bool lt = (od < dd) || (od == dd && ((unsigned)oj < (unsigned)j));
        bool take = (lower == up) ? lt : !lt;
        if (take) { dd = od; j = oj; }
      }
    }
    if (lane < KK) knn[((size_t)b * NN + iglob) * KK + lane] = j;
  }
}

// ---------------------------------------------------------------- stats
__global__ __launch_bounds__(512) void k_stats(const float* __restrict__ Pt,
                                               const float* __restrict__ Qt,
                                               const int* __restrict__ knn,
                                               float* __restrict__ mxT,
                                               float* __restrict__ mnT,
                                               double* __restrict__ sums) {
  __shared__ int ks[64 * KK];           // 5 KB
  __shared__ float rs[2][4][FOUT];      // 4 KB
  int L = blockIdx.x;                   // 512 blocks
  int b = (L & 7) | ((L >> 8) << 3);
  int nt = (L >> 3) & 31;
  int tid = threadIdx.x;
  int o = tid & 127, ng = tid >> 7;
  int nbase = nt * 64;
  for (int i = tid; i < 64 * KK; i += 512)
    ks[i] = knn[((size_t)b * NN + nbase) * KK + i];
  __syncthreads();
  const float* PtB = Pt + (size_t)b * NN * FOUT + o;
  const float* QtB = Qt + (size_t)b * NN * FOUT + o;
  float s1 = 0.f, s2 = 0.f;
  for (int nl = ng * 16; nl < ng * 16 + 16; ++nl) {
    int n = nbase + nl;
    float p = PtB[(size_t)n * FOUT];
    float vmx = -3.4e38f, vmn = 3.4e38f;
#pragma unroll
    for (int k = 0; k < KK; ++k) {
      float q = QtB[(size_t)ks[nl * KK + k] * FOUT];
      float y = p + q;
      s1 += y; s2 = fmaf(y, y, s2);
      vmx = fmaxf(vmx, y); vmn = fminf(vmn, y);
    }
    mxT[((size_t)b * NN + n) * FOUT + o] = vmx;
    mnT[((size_t)b * NN + n) * FOUT + o] = vmn;
  }
  rs[0][ng][o] = s1; rs[1][ng][o] = s2;
  __syncthreads();
  if (tid < FOUT) {
    float a = rs[0][0][tid] + rs[0][1][tid] + rs[0][2][tid] + rs[0][3][tid];
    float c = rs[1][0][tid] + rs[1][1][tid] + rs[1][2][tid] + rs[1][3][tid];
    atomicAdd(&sums[tid], (double)a);
    atomicAdd(&sums[FOUT + tid], (double)c);
  }
}

// ---------------------------------------------------------------- epilogue (finalize fused)
__global__ __launch_bounds__(256) void k_out(const float* __restrict__ mxT,
                                             const float* __restrict__ mnT,
                                             const double* __restrict__ sums,
                                             const float* __restrict__ gamma,
                                             const float* __restrict__ beta,
                                             float* __restrict__ out) {
  __shared__ float ssl[2][FOUT];
  __shared__ float ts[64][65];
  int tid = threadIdx.x;
  if (tid < FOUT) {
    double cnt = (double)Bb * NN * KK;
    double mean = sums[tid] / cnt;
    double var = sums[FOUT + tid] / cnt - mean * mean;
    double inv = 1.0 / sqrt(var + 1e-5);
    double scale = (double)gamma[tid] * inv;
    ssl[0][tid] = (float)scale;
    ssl[1][tid] = (float)((double)beta[tid] - mean * scale);
  }
  __syncthreads();
  int L = blockIdx.x;
  int b = (L & 7) | ((L >> 9) << 3);
  int nt = (L >> 3) & 31, ot = (L >> 8) & 1;
  int nbase = nt * 64, obase = ot * 64;
  for (int i = tid; i < 4096; i += 256) {
    int o_l = i & 63, n_l = i >> 6;
    int o = obase + o_l;
    const float* src = (ssl[0][o] >= 0.f) ? mxT : mnT;
    ts[o_l][n_l] = src[((size_t)b * NN + nbase + n_l) * FOUT + o];
  }
  __syncthreads();
  for (int i = tid; i < 4096; i += 256) {
    int n_l = i & 63, o_l = i >> 6;
    int o = obase + o_l;
    out[((size_t)b * FOUT + o) * NN + nbase + n_l] =
        fmaxf(fmaf(ssl[0][o], ts[o_l][n_l], ssl[1][o]), 0.f);
  }
}

// ---------------------------------------------------------------- launch
extern "C" void kernel_launch(void* const* d_in, const int* in_sizes, int n_in,
                              void* d_out, int out_size, void* d_ws, size_t ws_size,
                              hipStream_t stream) {
  const float* x     = (const float*)d_in[0];
  const float* W     = (const float*)d_in[1];
  const float* bias  = (const float*)d_in[2];
  const float* gamma = (const float*)d_in[3];
  const float* beta  = (const float*)d_in[4];
  float* out = (float*)d_out;

  char* ws = (char*)d_ws;
  const size_t PN = (size_t)Bb * FOUT * NN;          // 4,194,304
  float* Pt = (float*)ws;  ws += PN * 4;
  float* Qt = (float*)ws;  ws += PN * 4;
  float* mxT = (float*)ws; ws += PN * 4;             // 16 MB, aliased with xt*
  float* mnT = (float*)ws; ws += PN * 4;
  float* sq = (float*)ws;  ws += (size_t)Bb * NN * 4;
  int*   knn = (int*)ws;   ws += (size_t)Bb * NN * KK * 4;
  double* sums = (double*)ws; ws += 2 * FOUT * 8;

  // xth/xtl/xt32 alias mxT (4+4+8 MB); k_stats overwrites mxT only after
  // k_knn finished reading them (stream-ordered).
  unsigned short* xth = (unsigned short*)mxT;
  unsigned short* xtl = xth + (size_t)Bb * NN * FIN;
  float* xt32 = (float*)(xtl + (size_t)Bb * NN * FIN);

  hipMemsetAsync(sums, 0, 2 * FOUT * 8, stream);

  k_prep<<<dim3(NN / 64, Bb), 256, 0, stream>>>(x, xth, xtl, xt32, sq);
  k_pq<<<2048, 256, 0, stream>>>(x, W, bias, Pt, Qt);
  k_knn<<<1024, 512, 0, stream>>>(xth, xtl, xt32, sq, knn);
  k_stats<<<512, 512, 0, stream>>>(Pt, Qt, knn, mxT, mnT, sums);
  k_out<<<1024, 256, 0, stream>>>(mxT, mnT, sums, gamma, beta, out);
}

// Round 7
// 345.740 us; speedup vs baseline: 1.5788x; 1.1515x over previous
//
#include <hip/hip_runtime.h>
#include <hip/hip_bf16.h>

#define Bb   16
#define FIN  64
#define FOUT 128
#define NN   2048
#define KK   20
#define LCAP 32      // capture list size (approx top-32), refined to exact top-20
#define BUFD 112     // per-row LDS candidate buffer depth
#define TRIP 48      // set flush flag when cnt exceeds this (flush BEFORE next compact)

typedef unsigned long long u64;
typedef __attribute__((ext_vector_type(8))) __bf16 bf16x8;
typedef __attribute__((ext_vector_type(4))) float  f32x4;

static __device__ __forceinline__ unsigned short f2bf(float f) {
  unsigned u = __float_as_uint(f);
  unsigned r = (u + 0x7fff + ((u >> 16) & 1)) >> 16;   // RNE
  return (unsigned short)r;
}
static __device__ __forceinline__ float bf2f(unsigned short b) {
  return __uint_as_float(((unsigned)b) << 16);
}
static __device__ __forceinline__ void gll16(const void* g, void* l) {
  __builtin_amdgcn_global_load_lds(
      (const __attribute__((address_space(1))) unsigned int*)g,
      (__attribute__((address_space(3))) unsigned int*)l, 16, 0, 0);
}

// ascending bitonic sort of one u32 per lane across the full wave
static __device__ __forceinline__ unsigned sort64u(unsigned v, int lane) {
#pragma unroll
  for (int size = 2; size <= 64; size <<= 1) {
#pragma unroll
    for (int stride = size >> 1; stride; stride >>= 1) {
      unsigned o = __shfl_xor(v, stride);
      bool keepmin = (((lane & size) == 0) == ((lane & stride) == 0));
      bool lt = o < v;
      v = keepmin ? (lt ? o : v) : (lt ? v : o);
    }
  }
  return v;
}

// merge sorted-asc 32-list (lanes 0..31; lanes>=32 hold UMAX) with sorted-asc s
// (64 lanes); returns updated sorted-asc top-32 list (lanes>=32 = UMAX).
static __device__ __forceinline__ unsigned merge32u(unsigned lst, unsigned s, int lane) {
  unsigned rs = __shfl(s, 31 - (lane & 31));
  unsigned v = lst < rs ? lst : rs;       // bitonic
#pragma unroll
  for (int stride = 16; stride; stride >>= 1) {
    unsigned o = __shfl_xor(v, stride);
    unsigned mn = v < o ? v : o, mx = v < o ? o : v;
    v = ((lane & stride) == 0) ? mn : mx;
  }
  return (lane >= 32) ? 0xFFFFFFFFu : v;
}

static __device__ __forceinline__ void flushrow(unsigned& lst, int& cnt, unsigned& thr,
                                                const unsigned* bufrow, int lane) {
  for (int base = 0; base < cnt; base += 64) {
    unsigned c = (base + lane < cnt) ? bufrow[base + lane] : 0xFFFFFFFFu;
    c = sort64u(c, lane);
    lst = merge32u(lst, c, lane);
  }
  thr = __shfl(lst, 31);
  cnt = 0;
}

// ---------------------------------------------------------------- prep
// transpose x -> xt32[b][n][f]; bf16 hi/lo MFMA fragments xth/xtl; sq[b][n].
// Block (0,0) additionally packs W' = [W1-W2 ; W2] (256x64) into bf16 hi/lo
// A-fragments Wh/Wl for k_pq.
__global__ __launch_bounds__(256) void k_prep(const float* __restrict__ x,
                                              const float* __restrict__ W,
                                              unsigned short* __restrict__ xth,
                                              unsigned short* __restrict__ xtl,
                                              float* __restrict__ xt32,
                                              float* __restrict__ sq,
                                              unsigned short* __restrict__ Wh,
                                              unsigned short* __restrict__ Wl) {
  __shared__ float ts[FIN][65];
  int nt = blockIdx.x, b = blockIdx.y;
  int nbase = nt * 64, tid = threadIdx.x;
  if (nt == 0 && b == 0) {
    for (int u = tid; u < 32 * 512; u += 256) {
      int ot2 = u >> 9, lane = (u >> 3) & 63, e = u & 7;
      int o = (ot2 >> 1) * 16 + (lane & 15);
      int f = (ot2 & 1) * 32 + (lane >> 4) * 8 + e;
      float v = (o < FOUT) ? (W[o * 2 * FIN + f] - W[o * 2 * FIN + FIN + f])
                           : W[(o - FOUT) * 2 * FIN + FIN + f];
      unsigned short h = f2bf(v);
      Wh[u] = h;
      Wl[u] = f2bf(v - bf2f(h));
    }
  }
  for (int i = tid; i < 64 * 64; i += 256) {
    int f = i >> 6, j = i & 63;
    ts[f][j] = x[((size_t)b * FIN + f) * NN + nbase + j];
  }
  __syncthreads();
  if (tid < 64) {
    float s = 0.f;
#pragma unroll
    for (int f = 0; f < FIN; ++f) { float v = ts[f][tid]; s += v * v; }
    sq[b * NN + nbase + tid] = s;
  }
  for (int u = tid; u < 512; u += 256) {
    int lane = u & 63, ck = (u >> 6) & 1, pg = u >> 7;
    int j = pg * 16 + (lane & 15);
    int kg = lane >> 4;
    int fbase = ck * 32 + kg * 8;
    float v[8]; unsigned short h[8], l[8];
#pragma unroll
    for (int e = 0; e < 8; ++e) {
      v[e] = ts[fbase + e][j];
      h[e] = f2bf(v[e]);
      l[e] = f2bf(v[e] - bf2f(h[e]));
    }
    size_t po = (((size_t)b * (NN / 16) + (nbase >> 4) + pg) * 2 + ck) * 512 + lane * 8;
    ushort4* dh = (ushort4*)(xth + po);
    dh[0] = make_ushort4(h[0], h[1], h[2], h[3]);
    dh[1] = make_ushort4(h[4], h[5], h[6], h[7]);
    ushort4* dl = (ushort4*)(xtl + po);
    dl[0] = make_ushort4(l[0], l[1], l[2], l[3]);
    dl[1] = make_ushort4(l[4], l[5], l[6], l[7]);
    float* d32 = xt32 + ((size_t)b * NN + nbase + j) * FIN + fbase;
    *(float4*)d32       = make_float4(v[0], v[1], v[2], v[3]);
    *(float4*)(d32 + 4) = make_float4(v[4], v[5], v[6], v[7]);
  }
}

// ---------------------------------------------------------------- P/Q GEMM (MFMA)
// D[o][n] = W'[o][:]·x[b][:][n] via bf16 hi/lo 3-term MFMA; writes Pt/Qt[b][n][o]
// straight from the C-fragment layout (float4 per lane). No LDS.
__global__ __launch_bounds__(256) void k_pq(const unsigned short* __restrict__ xth,
                                            const unsigned short* __restrict__ xtl,
                                            const unsigned short* __restrict__ Wh,
                                            const unsigned short* __restrict__ Wl,
                                            const float* __restrict__ bias,
                                            float* __restrict__ Pt,
                                            float* __restrict__ Qt) {
  int L = blockIdx.x;                    // 512 blocks
  int b = (L & 7) | ((L >> 8) << 3);
  int nt64 = (L >> 3) & 31;
  int tid = threadIdx.x, lane = tid & 63, w = tid >> 6;
  bf16x8 aH[4][2], aL[4][2];
#pragma unroll
  for (int t = 0; t < 4; ++t) {
    int ot = w * 4 + t;
#pragma unroll
    for (int ck = 0; ck < 2; ++ck) {
      aH[t][ck] = *(const bf16x8*)(Wh + ((ot * 2 + ck) << 9) + lane * 8);
      aL[t][ck] = *(const bf16x8*)(Wl + ((ot * 2 + ck) << 9) + lane * 8);
    }
  }
  bool isP = (w < 2);
  int orow = (lane >> 4) * 4;
  float4 b4[4];
#pragma unroll
  for (int t = 0; t < 4; ++t) {
    int o = (w * 4 + t) * 16 + orow;
    b4[t] = isP ? *(const float4*)&bias[o] : make_float4(0.f, 0.f, 0.f, 0.f);
  }
  const unsigned short* xhB = xth + (size_t)b * (NN / 16) * 1024;
  const unsigned short* xlB = xtl + (size_t)b * (NN / 16) * 1024;
  float* dstB = (isP ? Pt : Qt) + (size_t)b * NN * FOUT;
#pragma unroll
  for (int nt = 0; nt < 4; ++nt) {
    int p = nt64 * 4 + nt;
    size_t pb = (size_t)p * 1024 + lane * 8;
    bf16x8 bh0 = *(const bf16x8*)(xhB + pb);
    bf16x8 bh1 = *(const bf16x8*)(xhB + pb + 512);
    bf16x8 bl0 = *(const bf16x8*)(xlB + pb);
    bf16x8 bl1 = *(const bf16x8*)(xlB + pb + 512);
    int n = p * 16 + (lane & 15);
#pragma unroll
    for (int t = 0; t < 4; ++t) {
      f32x4 acc = {0.f, 0.f, 0.f, 0.f};
      acc = __builtin_amdgcn_mfma_f32_16x16x32_bf16(aH[t][0], bh0, acc, 0, 0, 0);
      acc = __builtin_amdgcn_mfma_f32_16x16x32_bf16(aH[t][1], bh1, acc, 0, 0, 0);
      acc = __builtin_amdgcn_mfma_f32_16x16x32_bf16(aH[t][0], bl0, acc, 0, 0, 0);
      acc = __builtin_amdgcn_mfma_f32_16x16x32_bf16(aH[t][1], bl1, acc, 0, 0, 0);
      acc = __builtin_amdgcn_mfma_f32_16x16x32_bf16(aL[t][0], bh0, acc, 0, 0, 0);
      acc = __builtin_amdgcn_mfma_f32_16x16x32_bf16(aL[t][1], bh1, acc, 0, 0, 0);
      int o = ((w * 4 + t) * 16 + orow) & 127;
      *(float4*)&dstB[(size_t)n * FOUT + o] =
          make_float4(acc[0] + b4[t].x, acc[1] + b4[t].y,
                      acc[2] + b4[t].z, acc[3] + b4[t].w);
    }
  }
}

// ---------------------------------------------------------------- kNN
// MFMA distance tiles -> packed u32 keys -> ballot+scatter candidate buffer
// -> BLOCK-UNIFORM flush BEFORE compaction (flag deferred one tile) ->
// exact fp64 refine.  LDS ~38.6KB -> 4 blocks/CU, grid 1024 = exactly 4/CU.
__global__ __launch_bounds__(512, 8) void k_knn(const unsigned short* __restrict__ xth,
                                                const unsigned short* __restrict__ xtl,
                                                const float* __restrict__ xt32,
                                                const float* __restrict__ sq,
                                                int* __restrict__ knn) {
  __shared__ unsigned short BjH[4096];   // 8 KB
  __shared__ unsigned short BjL[4096];   // 8 KB
  __shared__ unsigned dtk[32][66];       // 8.25 KB packed keys
  __shared__ unsigned buf[32 * BUFD];    // 14 KB candidate buffers
  __shared__ float sqi_s[32], sqj_s[64];
  __shared__ unsigned flg[2];

  int L = blockIdx.x;
  int b = (L & 7) | ((L >> 9) << 3);     // XCD-local b
  int it = (L >> 3) & 63;
  int ibase = it * 32, tid = threadIdx.x;
  int lane = tid & 63, w = tid >> 6;     // 8 waves
  int tr = w >> 2, tc = w & 3;           // MFMA tile (2x4)

  const unsigned short* xhB = xth + (size_t)b * (NN / 16) * 1024;
  const unsigned short* xlB = xtl + (size_t)b * (NN / 16) * 1024;

  size_t pa = ((size_t)(ibase >> 4) + tr) * 1024;
  bf16x8 ah0 = *(const bf16x8*)(xhB + pa +       lane * 8);
  bf16x8 ah1 = *(const bf16x8*)(xhB + pa + 512 + lane * 8);
  bf16x8 al0 = *(const bf16x8*)(xlB + pa +       lane * 8);
  bf16x8 al1 = *(const bf16x8*)(xlB + pa + 512 + lane * 8);

  if (tid < 32) sqi_s[tid] = sq[b * NN + ibase + tid];
  if (tid < 2) flg[tid] = 0;

  unsigned lst[4], thr[4]; int cnt[4];
#pragma unroll
  for (int r = 0; r < 4; ++r) { lst[r] = 0xFFFFFFFFu; thr[r] = 0xFFFFFFFFu; cnt[r] = 0; }

  gll16(xhB + tid * 8, BjH + tid * 8);
  gll16(xlB + tid * 8, BjL + tid * 8);
  if (tid < 64) sqj_s[tid] = sq[b * NN + tid];

  for (int jt = 0; jt < NN / 64; ++jt) {
    __syncthreads();                     // bar1: staged tile + sqj ready
    if (tid == 0) flg[(jt & 1) ^ 1] = 0; // clear slot read last tile
    {
      int jbase = jt * 64;
      bf16x8 bh0 = *(const bf16x8*)(BjH + (tc * 2 + 0) * 512 + lane * 8);
      bf16x8 bh1 = *(const bf16x8*)(BjH + (tc * 2 + 1) * 512 + lane * 8);
      bf16x8 bl0 = *(const bf16x8*)(BjL + (tc * 2 + 0) * 512 + lane * 8);
      bf16x8 bl1 = *(const bf16x8*)(BjL + (tc * 2 + 1) * 512 + lane * 8);
      f32x4 acc = {0.f, 0.f, 0.f, 0.f};
      acc = __builtin_amdgcn_mfma_f32_16x16x32_bf16(ah0, bh0, acc, 0, 0, 0);
      acc = __builtin_amdgcn_mfma_f32_16x16x32_bf16(ah1, bh1, acc, 0, 0, 0);
      acc = __builtin_amdgcn_mfma_f32_16x16x32_bf16(ah0, bl0, acc, 0, 0, 0);
      acc = __builtin_amdgcn_mfma_f32_16x16x32_bf16(ah1, bl1, acc, 0, 0, 0);
      acc = __builtin_amdgcn_mfma_f32_16x16x32_bf16(al0, bh0, acc, 0, 0, 0);
      acc = __builtin_amdgcn_mfma_f32_16x16x32_bf16(al1, bh1, acc, 0, 0, 0);
      int jl = tc * 16 + (lane & 15);
      int jglob = jbase + jl;
      float sj = sqj_s[jl];
#pragma unroll
      for (int e = 0; e < 4; ++e) {
        int il = tr * 16 + (lane >> 4) * 4 + e;
        float d = fmaxf(sqi_s[il] + sj - 2.f * acc[e], 0.f);
        unsigned key = (__float_as_uint(d) & 0xFFFFF800u) | (unsigned)jglob;
        if (jglob == ibase + il) key = 0xFFFFFFFFu;   // exclude self
        dtk[il][jl] = key;
      }
    }
    __syncthreads();                     // bar2: keys ready, Bj free
    int doflush = flg[jt & 1];           // set during previous tile
    if (jt + 1 < NN / 64) {              // prefetch next tile under selection
      const unsigned short* sh = xhB + (size_t)(jt + 1) * 4096;
      const unsigned short* sl = xlB + (size_t)(jt + 1) * 4096;
      gll16(sh + tid * 8, BjH + tid * 8);
      gll16(sl + tid * 8, BjL + tid * 8);
      if (tid < 64) sqj_s[tid] = sq[b * NN + (jt + 1) * 64 + tid];
    }
    // ---- block-uniform flush FIRST (empties buf, freshens thr)
    if (doflush) {
#pragma unroll
      for (int r = 0; r < 4; ++r)
        flushrow(lst[r], cnt[r], thr[r], &buf[(w * 4 + r) * BUFD], lane);
    }
    // ---- compact survivors (1 ballot + scatter per row)
    u64 below = (1ull << lane) - 1;
#pragma unroll
    for (int r = 0; r < 4; ++r) {
      unsigned key = dtk[w * 4 + r][lane];
      u64 m = __ballot(key < thr[r]);
      if (m) {
        if (key < thr[r]) buf[(w * 4 + r) * BUFD + cnt[r] + __popcll(m & below)] = key;
        cnt[r] += (int)__popcll(m);
      }
    }
    bool trip = cnt[0] > TRIP || cnt[1] > TRIP || cnt[2] > TRIP || cnt[3] > TRIP;
    if (trip && lane == 0) flg[(jt & 1) ^ 1] = 1;
  }
  // final flush
#pragma unroll
  for (int r = 0; r < 4; ++r)
    flushrow(lst[r], cnt[r], thr[r], &buf[(w * 4 + r) * BUFD], lane);

  // ---- exact fp64 refine of the 32 captured candidates, emit top-20
  const float* x32B = xt32 + (size_t)b * NN * FIN;
#pragma unroll
  for (int r = 0; r < 4; ++r) {
    int row = w * 4 + r, iglob = ibase + row;
    int j = (lane < LCAP) ? (int)(lst[r] & 0x7FFu) : -1;
    double dd = 1e300;
    if (j >= 0) {
      const float4* xi4 = (const float4*)(x32B + (size_t)iglob * FIN);
      const float4* xj4 = (const float4*)(x32B + (size_t)j * FIN);
      double s = 0.0;
#pragma unroll
      for (int q = 0; q < 16; ++q) {
        float4 a = xi4[q], c = xj4[q];
        double d0 = (double)a.x - (double)c.x;
        double d1 = (double)a.y - (double)c.y;
        double d2 = (double)a.z - (double)c.z;
        double d3 = (double)a.w - (double)c.w;
        s += d0 * d0 + d1 * d1 + d2 * d2 + d3 * d3;
      }
      dd = s;
    }
#pragma unroll
    for (int size = 2; size <= 64; size <<= 1) {
#pragma unroll
      for (int stride = size >> 1; stride; stride >>= 1) {
        double od = __shfl_xor(dd, stride);
        int    oj = __shfl_xor(j, stride);
        bool up = (lane & size) == 0;
        bool lower = (lane & stride) == 0;
        bool lt = (od < dd) || (od == dd && ((unsigned)oj < (unsigned)j));
        bool take = (lower == up) ? lt : !lt;
        if (take) { dd = od; j = oj; }
      }
    }
    if (lane < KK) knn[((size_t)b * NN + iglob) * KK + lane] = j;
  }
}

// ---------------------------------------------------------------- stats
__global__ __launch_bounds__(512) void k_stats(const float* __restrict__ Pt,
                                               const float* __restrict__ Qt,
                                               const int* __restrict__ knn,
                                               float* __restrict__ mxT,
                                               float* __restrict__ mnT,
                                               double* __restrict__ sums) {
  __shared__ int ks[64 * KK];           // 5 KB
  __shared__ float rs[2][4][FOUT];      // 4 KB
  int L = blockIdx.x;                   // 512 blocks
  int b = (L & 7) | ((L >> 8) << 3);
  int nt = (L >> 3) & 31;
  int tid = threadIdx.x;
  int o = tid & 127, ng = tid >> 7;
  int nbase = nt * 64;
  for (int i = tid; i < 64 * KK; i += 512)
    ks[i] = knn[((size_t)b * NN + nbase) * KK + i];
  __syncthreads();
  const float* PtB = Pt + (size_t)b * NN * FOUT + o;
  const float* QtB = Qt + (size_t)b * NN * FOUT + o;
  float s1 = 0.f, s2 = 0.f;
  for (int nl = ng * 16; nl < ng * 16 + 16; ++nl) {
    int n = nbase + nl;
    float p = PtB[(size_t)n * FOUT];
    float vmx = -3.4e38f, vmn = 3.4e38f;
#pragma unroll
    for (int k = 0; k < KK; ++k) {
      float q = QtB[(size_t)ks[nl * KK + k] * FOUT];
      float y = p + q;
      s1 += y; s2 = fmaf(y, y, s2);
      vmx = fmaxf(vmx, y); vmn = fminf(vmn, y);
    }
    mxT[((size_t)b * NN + n) * FOUT + o] = vmx;
    mnT[((size_t)b * NN + n) * FOUT + o] = vmn;
  }
  rs[0][ng][o] = s1; rs[1][ng][o] = s2;
  __syncthreads();
  if (tid < FOUT) {
    float a = rs[0][0][tid] + rs[0][1][tid] + rs[0][2][tid] + rs[0][3][tid];
    float c = rs[1][0][tid] + rs[1][1][tid] + rs[1][2][tid] + rs[1][3][tid];
    atomicAdd(&sums[tid], (double)a);
    atomicAdd(&sums[FOUT + tid], (double)c);
  }
}

// ---------------------------------------------------------------- epilogue (finalize fused)
__global__ __launch_bounds__(256) void k_out(const float* __restrict__ mxT,
                                             const float* __restrict__ mnT,
                                             const double* __restrict__ sums,
                                             const float* __restrict__ gamma,
                                             const float* __restrict__ beta,
                                             float* __restrict__ out) {
  __shared__ float ssl[2][FOUT];
  __shared__ float ts[64][65];
  int tid = threadIdx.x;
  if (tid < FOUT) {
    double cnt = (double)Bb * NN * KK;
    double mean = sums[tid] / cnt;
    double var = sums[FOUT + tid] / cnt - mean * mean;
    double inv = 1.0 / sqrt(var + 1e-5);
    double scale = (double)gamma[tid] * inv;
    ssl[0][tid] = (float)scale;
    ssl[1][tid] = (float)((double)beta[tid] - mean * scale);
  }
  __syncthreads();
  int L = blockIdx.x;
  int b = (L & 7) | ((L >> 9) << 3);
  int nt = (L >> 3) & 31, ot = (L >> 8) & 1;
  int nbase = nt * 64, obase = ot * 64;
  for (int i = tid; i < 4096; i += 256) {
    int o_l = i & 63, n_l = i >> 6;
    int o = obase + o_l;
    const float* src = (ssl[0][o] >= 0.f) ? mxT : mnT;
    ts[o_l][n_l] = src[((size_t)b * NN + nbase + n_l) * FOUT + o];
  }
  __syncthreads();
  for (int i = tid; i < 4096; i += 256) {
    int n_l = i & 63, o_l = i >> 6;
    int o = obase + o_l;
    out[((size_t)b * FOUT + o) * NN + nbase + n_l] =
        fmaxf(fmaf(ssl[0][o], ts[o_l][n_l], ssl[1][o]), 0.f);
  }
}

// ---------------------------------------------------------------- launch
extern "C" void kernel_launch(void* const* d_in, const int* in_sizes, int n_in,
                              void* d_out, int out_size, void* d_ws, size_t ws_size,
                              hipStream_t stream) {
  const float* x     = (const float*)d_in[0];
  const float* W     = (const float*)d_in[1];
  const float* bias  = (const float*)d_in[2];
  const float* gamma = (const float*)d_in[3];
  const float* beta  = (const float*)d_in[4];
  float* out = (float*)d_out;

  char* ws = (char*)d_ws;
  const size_t PN = (size_t)Bb * FOUT * NN;          // 4,194,304
  float* Pt = (float*)ws;  ws += PN * 4;
  float* Qt = (float*)ws;  ws += PN * 4;
  float* mxT = (float*)ws; ws += PN * 4;             // 16 MB, aliased with xt*
  float* mnT = (float*)ws; ws += PN * 4;
  float* sq = (float*)ws;  ws += (size_t)Bb * NN * 4;
  int*   knn = (int*)ws;   ws += (size_t)Bb * NN * KK * 4;
  double* sums = (double*)ws; ws += 2 * FOUT * 8;
  unsigned short* Wh = (unsigned short*)ws; ws += 32 * 512 * 2;
  unsigned short* Wl = (unsigned short*)ws; ws += 32 * 512 * 2;

  // xth/xtl/xt32 alias mxT (4+4+8 MB); k_stats overwrites mxT only after
  // k_knn finished reading them (stream-ordered).
  unsigned short* xth = (unsigned short*)mxT;
  unsigned short* xtl = xth + (size_t)Bb * NN * FIN;
  float* xt32 = (float*)(xtl + (size_t)Bb * NN * FIN);

  hipMemsetAsync(sums, 0, 2 * FOUT * 8, stream);

  k_prep<<<dim3(NN / 64, Bb), 256, 0, stream>>>(x, W, xth, xtl, xt32, sq, Wh, Wl);
  k_pq<<<512, 256, 0, stream>>>(xth, xtl, Wh, Wl, bias, Pt, Qt);
  k_knn<<<1024, 512, 0, stream>>>(xth, xtl, xt32, sq, knn);
  k_stats<<<512, 512, 0, stream>>>(Pt, Qt, knn, mxT, mnT, sums);
  k_out<<<1024, 256, 0, stream>>>(mxT, mnT, sums, gamma, beta, out);
}